// Round 17
// baseline (830.247 us; speedup 1.0000x reference)
//
#include <hip/hip_runtime.h>

typedef _Float16 f16;
typedef _Float16 f16x8 __attribute__((ext_vector_type(8)));
typedef _Float16 f16x4 __attribute__((ext_vector_type(4)));
typedef float    f32x4 __attribute__((ext_vector_type(4)));
typedef float    f32x16 __attribute__((ext_vector_type(16)));

#define MFMA16(a,b,c) __builtin_amdgcn_mfma_f32_16x16x32_f16(a,b,c,0,0,0)
#define MFMA32(a,b,c) __builtin_amdgcn_mfma_f32_32x32x16_f16(a,b,c,0,0,0)

#define AS1 __attribute__((address_space(1)))
#define AS3 __attribute__((address_space(3)))

#define NPIX 65536
// activation layout (halves): [row 258][cb 7][h 2][k16 2][kh 2][px 258][8]
#define PXS   8
#define KHS   2064      // 258*8
#define K16S  4128
#define HS    8256
#define CBS   16512
#define ROWH  115584    // halves per row
#define RBYTES 231168
#define SBUF  ((size_t)258*RBYTES)   // 59,641,344 B

// conv weight pack (halves): 117 LIVE slices per layer, slice = [sel 2][ob 7][lane 64][8]
#define PKSUB  7168
#define PK_CONV 903168   // per-layer stride (126 slots; tail unused)
#define NMICRO 117

// last (1x1) pack strides (halves)
#define PKL_CB  5120
#define PKL_BI  35840

#define ASTG 14336

// ---------------- weight packing: 3x3 convs, 32x32 A-fragment order ----------------
__global__ void k_pack_conv(const float* __restrict__ head_w,
                            const float* __restrict__ conv_w,
                            f16* __restrict__ dst)
{
    int t = blockIdx.x*256 + threadIdx.x;
    int lane = t & 63; t >>= 6;
    int ob  = t % 7;  t /= 7;
    int sel = t & 1;  t >>= 1;
    int kx  = t % 3;  t /= 3;
    int k16 = t & 1;  t >>= 1;
    int cb  = t % 7;  t /= 7;
    int ky  = t % 3;  t /= 3;
    int li  = t;
    if (li >= 4) return;
    if (cb == 6 && k16 == 1) return;          // dead slice: ic 208..223 all zero
    const float* W = (li == 0) ? head_w : (conv_w + (size_t)(li-1)*196*196*9);
    int oc  = ob*32 + (lane & 31);
    int ic0 = cb*32 + k16*16 + (lane >> 5)*8;
    int tap = ky*3 + kx;
    f16x8 v;
#pragma unroll
    for (int j = 0; j < 8; ++j) {
        int ic = ic0 + j;
        float x = 0.f;
        if (oc < 196 && ic < 196) x = W[((size_t)oc*196 + ic)*9 + tap];
        f16 h = (f16)x;
        v[j] = (sel == 0) ? h : (f16)(x - (float)h);
    }
    int pos = ky*39 + ((cb < 6) ? (cb*6 + k16*3 + kx) : (36 + kx));
    *(f16x8*)(dst + (size_t)li*PK_CONV + (size_t)pos*PKSUB
              + (size_t)(sel*7 + ob)*512 + (size_t)lane*8) = v;
}

__global__ void k_pack_last(const float* __restrict__ last_w, f16* __restrict__ dst)
{
    int t = blockIdx.x*256 + threadIdx.x;
    if (t >= 4*7*5*2*64) return;
    int lane = t & 63; t >>= 6;
    int sel  = t & 1;  t >>= 1;
    int ob   = t % 5;  t /= 5;
    int cb   = t % 7;  t /= 7;
    int bi   = t;
    int oc = ob*16 + (lane & 15);
    int k0 = cb*32 + (lane >> 4)*8;
    f16x8 v;
#pragma unroll
    for (int j = 0; j < 8; ++j) {
        int k = k0 + j;
        float x = 0.f;
        if (oc < 68 && k < 196) x = last_w[(size_t)oc*784 + bi*196 + k];
        f16 h = (f16)x;
        v[j] = (sel == 0) ? h : (f16)(x - (float)h);
    }
    *(f16x8*)(dst + (((size_t)((bi*7+cb)*5 + ob)*2 + sel)*64 + lane)*8) = v;
}

// ---------------- zero the halo px-slots (0 and 257) of every row/slice ----------------
__global__ void k_zero_halo(f16* __restrict__ bufA, f16* __restrict__ bufB)
{
    int c = blockIdx.x*256 + threadIdx.x;
    int end = c & 1; c >>= 1;
    int kh  = c & 1; c >>= 1;
    int k16 = c & 1; c >>= 1;
    int h   = c & 1; c >>= 1;
    int cb  = c % 7; c /= 7;
    int row = c % 258; c /= 258;
    if (c >= 2) return;
    f16* base = (c == 0) ? bufA : bufB;
    f16* p = base + (size_t)row*ROWH + cb*CBS + h*HS + k16*K16S + kh*KHS + (end ? 257 : 0)*PXS;
    f16x8 z = {(f16)0,(f16)0,(f16)0,(f16)0,(f16)0,(f16)0,(f16)0,(f16)0};
    *(f16x8*)p = z;
}

// ---------------- warp + concat → x0 ----------------
struct Gath { int o00,o01,o10,o11; float w00,w01,w10,w11; };

__device__ inline Gath mk_gath(float pxf, float pyf)
{
    float x0 = floorf(pxf), y0 = floorf(pyf);
    float x1 = x0 + 1.f, y1 = y0 + 1.f;
    float wx1 = pxf - x0, wx0 = 1.f - wx1;
    float wy1 = pyf - y0, wy0 = 1.f - wy1;
    bool vx0 = (x0 >= 0.f) && (x0 <= 255.f);
    bool vx1 = (x1 >= 0.f) && (x1 <= 255.f);
    bool vy0 = (y0 >= 0.f) && (y0 <= 255.f);
    bool vy1 = (y1 >= 0.f) && (y1 <= 255.f);
    int ix0 = min(max((int)x0, 0), 255);
    int ix1 = min(max((int)x1, 0), 255);
    int iy0 = min(max((int)y0, 0), 255);
    int iy1 = min(max((int)y1, 0), 255);
    Gath g;
    g.o00 = iy0*256 + ix0; g.w00 = (vx0 && vy0) ? wx0*wy0 : 0.f;
    g.o01 = iy0*256 + ix1; g.w01 = (vx1 && vy0) ? wx1*wy0 : 0.f;
    g.o10 = iy1*256 + ix0; g.w10 = (vx0 && vy1) ? wx0*wy1 : 0.f;
    g.o11 = iy1*256 + ix1; g.w11 = (vx1 && vy1) ? wx1*wy1 : 0.f;
    return g;
}

__device__ inline void store4n(f16* __restrict__ rowb, int slot, int c0,
                               float a, float b, float c, float d)
{
    f16x4 hi, lo;
    f16 h;
    h = (f16)a; hi[0] = h; lo[0] = (f16)(a - (float)h);
    h = (f16)b; hi[1] = h; lo[1] = (f16)(b - (float)h);
    h = (f16)c; hi[2] = h; lo[2] = (f16)(c - (float)h);
    h = (f16)d; hi[3] = h; lo[3] = (f16)(d - (float)h);
    int cb = c0 >> 5, w32 = c0 & 31;
    f16* p = rowb + cb*CBS + (w32 >> 4)*K16S + ((w32 >> 3) & 1)*KHS
                 + (size_t)slot*PXS + (w32 & 7);
    *(f16x4*)p        = hi;
    *(f16x4*)(p + HS) = lo;
}

__global__ void k_warp_concat(const float* __restrict__ f0, const float* __restrict__ f1,
                              const float* __restrict__ fd, const float* __restrict__ flow,
                              f16* __restrict__ out)
{
    int px = blockIdx.x*256 + threadIdx.x;
    int row = px >> 8, col = px & 255;
    f16* rowb = out + (size_t)(row+1)*ROWH;
    int slot = col + 1;
    Gath g0 = mk_gath((float)col + flow[px],          (float)row + flow[NPIX   + px]);
    Gath g1 = mk_gath((float)col + flow[2*NPIX + px], (float)row + flow[3*NPIX + px]);
#pragma unroll
    for (int c = 0; c < 64; c += 4) {
        float v[4];
#pragma unroll
        for (int r = 0; r < 4; ++r) {
            const float* im = f0 + (size_t)(c+r)*NPIX;
            v[r] = g0.w00*im[g0.o00] + g0.w01*im[g0.o01] + g0.w10*im[g0.o10] + g0.w11*im[g0.o11];
        }
        store4n(rowb, slot, c, v[0], v[1], v[2], v[3]);
    }
#pragma unroll
    for (int c = 0; c < 64; c += 4) {
        float v[4];
#pragma unroll
        for (int r = 0; r < 4; ++r) {
            const float* im = f1 + (size_t)(c+r)*NPIX;
            v[r] = g1.w00*im[g1.o00] + g1.w01*im[g1.o01] + g1.w10*im[g1.o10] + g1.w11*im[g1.o11];
        }
        store4n(rowb, slot, 64 + c, v[0], v[1], v[2], v[3]);
    }
#pragma unroll
    for (int c = 0; c < 64; c += 4) {
        store4n(rowb, slot, 128 + c, fd[(size_t)(c+0)*NPIX + px], fd[(size_t)(c+1)*NPIX + px],
                                     fd[(size_t)(c+2)*NPIX + px], fd[(size_t)(c+3)*NPIX + px]);
    }
    store4n(rowb, slot, 192, flow[px], flow[NPIX+px], flow[2*NPIX+px], flow[3*NPIX+px]);
#pragma unroll
    for (int c = 196; c < 224; c += 4) store4n(rowb, slot, c, 0.f, 0.f, 0.f, 0.f);
}

// ---------------- 3x3 conv: R15 micro-body, 1024 x 128-thread blocks ---------------
// Block = 2 waves = 64-px tile; 4 independent blocks/CU → LDS and MFMA phases of
// different blocks overlap (no cross-block lockstep). Wave = 7 ob32 x one 32-px tile.
// Per micro: stage next A slice (14KB dbuf, global_load_lds) + next B (2 reg loads);
// 14 ds_read_b128 + 21 MFMA; one (2-wave) __syncthreads. 117 live micros.
__global__ __launch_bounds__(128, 2)
void k_conv32(const f16* __restrict__ in, f16* __restrict__ out,
              const f16* __restrict__ pack, const float* __restrict__ alpha,
              const float* __restrict__ mask)
{
    __shared__ __align__(16) char As[2][ASTG];

    int bid = blockIdx.x;
    int wg  = (bid & 7)*128 + (bid >> 3);     // bijective XCD swizzle (1024 % 8 == 0)
    int row  = wg >> 2;
    int quad = wg & 3;
    int tid  = threadIdx.x;
    int lane = tid & 63;
    int w    = tid >> 6;
    int pxt  = quad*2 + w;
    int l31 = lane & 31, lk = lane >> 5;

    f32x16 acc[7];
#pragma unroll
    for (int o = 0; o < 7; ++o)
#pragma unroll
        for (int e = 0; e < 16; ++e) acc[o][e] = 0.f;

    // stage A slice (896 x 16B chunks), linear both sides; 7 DMA/thread
    auto stage = [&](int b, const f16* src) {
#pragma unroll
        for (int u = 0; u < 7; ++u) {
            int c = tid + u*128;
            __builtin_amdgcn_global_load_lds(
                (const AS1 void*)(src + (size_t)c*8),
                (AS3 void*)(&As[b][0] + c*16), 16, 0, 0);
        }
    };

    auto lB = [&](const f16* bp, f16x8& H, f16x8& L) {
        H = *(const f16x8*)bp;
        L = *(const f16x8*)(bp + HS);
    };

    // B base: stored slot = pxt*32 + l31 + kx (halo handles the kx-1 shift)
    const f16* bcol = in + (size_t)lk*KHS + (size_t)(pxt*32 + l31)*PXS;

    f16x8 Bh0, Bl0, Bh1, Bl1;
    stage(0, pack);
    lB(bcol + (size_t)row*ROWH, Bh0, Bl0);
    __syncthreads();

    int bsel = 0, q = 0;
    for (int ky = 0; ky < 3; ++ky) {
        const f16* brow = bcol + (size_t)(row + ky)*ROWH;
        for (int cb = 0; cb < 7; ++cb) {
            const f16* bcb = brow + cb*CBS;
            const f16* bnext = (cb < 6) ? (bcb + CBS) : (brow + ROWH);
            int nk16 = (cb == 6) ? 1 : 2;
            for (int k16 = 0; k16 < 2; ++k16) {
                if (k16 >= nk16) break;
#pragma unroll
                for (int kx = 0; kx < 3; ++kx) {
                    bool last = (q == NMICRO - 1);
                    if (!last) {
                        stage(bsel ^ 1, pack + (size_t)(q+1)*PKSUB);
                        const f16* nb;
                        if (kx < 2)                  nb = bcb + k16*K16S + (kx+1)*PXS;
                        else if (k16 == 0 && cb < 6) nb = bcb + K16S;
                        else                         nb = bnext;
                        lB(nb, Bh1, Bl1);
                    }
                    const char* ab = &As[bsel][0];
                    __builtin_amdgcn_s_setprio(1);
#pragma unroll
                    for (int o = 0; o < 7; ++o) {
                        f16x8 Ah = *(const f16x8*)(ab + o*1024 + lane*16);
                        f16x8 Al = *(const f16x8*)(ab + (7+o)*1024 + lane*16);
                        acc[o] = MFMA32(Ah, Bh0, acc[o]);
                        acc[o] = MFMA32(Al, Bh0, acc[o]);
                        acc[o] = MFMA32(Ah, Bl0, acc[o]);
                    }
                    __builtin_amdgcn_s_setprio(0);
                    __syncthreads();
                    bsel ^= 1; ++q;
                    Bh0 = Bh1; Bl0 = Bl1;
                }
            }
        }
    }

    // epilogue: prelu * mask, split-f16 store into the channel-major layout
    float mv = mask[row*256 + pxt*32 + l31];
    f16* orow = out + (size_t)(row+1)*ROWH + (size_t)(pxt*32 + l31 + 1)*PXS + lk*4;
#pragma unroll
    for (int o = 0; o < 7; ++o) {
#pragma unroll
        for (int qg = 0; qg < 4; ++qg) {
            int oc0 = o*32 + 8*qg + 4*lk;
            f32x4 a4 = *(const f32x4*)(alpha + min(oc0, 192));
            f16x4 hi, lo;
#pragma unroll
            for (int e = 0; e < 4; ++e) {
                float v = acc[o][qg*4 + e];
                v = (v >= 0.f ? v : a4[e]*v) * mv;
                f16 h = (f16)v;
                hi[e] = h;
                lo[e] = (f16)(v - (float)h);
            }
            f16* p = orow + o*CBS + (qg >> 1)*K16S + (qg & 1)*KHS;
            *(f16x4*)p        = hi;
            *(f16x4*)(p + HS) = lo;
        }
    }
}

// ---------------- incremental 1x1 last-conv: acc[px][72] (+= / init with bias) ----------------
__global__ __launch_bounds__(256, 4)
void k_acc_last(const f16* __restrict__ in, const f16* __restrict__ pack,
                const float* __restrict__ bias, float* __restrict__ accp, int bi)
{
    int lane = threadIdx.x & 63;
    int wid  = (blockIdx.x << 2) | (threadIdx.x >> 6);
    int row  = wid >> 3;
    int col0 = (wid & 7) << 5;
    int l15 = lane & 15, lk = lane >> 4;

    f32x4 acc[5][2];
#pragma unroll
    for (int i = 0; i < 5; ++i)
#pragma unroll
        for (int j = 0; j < 2; ++j)
            acc[i][j] = (f32x4){0.f, 0.f, 0.f, 0.f};

    const f16* bb = in + (size_t)(row+1)*ROWH + (size_t)(col0 + l15 + 1)*PXS
                  + (lk >> 1)*K16S + (lk & 1)*KHS;
    const f16* ap = pack + (size_t)bi*PKL_BI + (size_t)lane*8;
    for (int cb = 0; cb < 7; ++cb) {
        f16x8 bh[2], bl[2];
#pragma unroll
        for (int pb = 0; pb < 2; ++pb) {
            const f16* p = bb + cb*CBS + pb*16*PXS;
            bh[pb] = *(const f16x8*)p;
            bl[pb] = *(const f16x8*)(p + HS);
        }
        const f16* a = ap + cb*PKL_CB;
#pragma unroll
        for (int ob = 0; ob < 5; ++ob) {
            f16x8 ah = *(const f16x8*)(a + ob*1024);
            f16x8 al = *(const f16x8*)(a + ob*1024 + 512);
#pragma unroll
            for (int pb = 0; pb < 2; ++pb) {
                acc[ob][pb] = MFMA16(ah, bh[pb], acc[ob][pb]);
                acc[ob][pb] = MFMA16(ah, bl[pb], acc[ob][pb]);
                acc[ob][pb] = MFMA16(al, bh[pb], acc[ob][pb]);
            }
        }
    }
#pragma unroll
    for (int ob = 0; ob < 5; ++ob) {
        int oc0 = ob*16 + lk*4;
        if (oc0 >= 72) continue;           // accp stride is 72 floats
#pragma unroll
        for (int pb = 0; pb < 2; ++pb) {
            int px = row*256 + col0 + pb*16 + l15;
            float* dst = accp + (size_t)px*72 + oc0;
            f32x4 d = acc[ob][pb];
            if (bi == 0) {
                f32x4 b4;
#pragma unroll
                for (int r = 0; r < 4; ++r) b4[r] = bias[min(oc0 + r, 67)];
                *(f32x4*)dst = d + b4;
            } else {
                *(f32x4*)dst = *(const f32x4*)dst + d;
            }
        }
    }
}

// ---------------- smn = 3x3 conv(acc[4:68]) + mask_b  (plain f32) ----------------
__global__ void k_smn(const float* __restrict__ accp, const float* __restrict__ mw,
                      const float* __restrict__ mb, float* __restrict__ smn)
{
    int px = blockIdx.x*256 + threadIdx.x;
    int row = px >> 8, col = px & 255;
    float s0 = mb[0], s1 = mb[1];
    for (int ky = 0; ky < 3; ++ky) {
        int r = row + ky - 1;
        if ((unsigned)r > 255u) continue;
        for (int kx = 0; kx < 3; ++kx) {
            int c = col + kx - 1;
            if ((unsigned)c > 255u) continue;
            const float* ab = accp + ((size_t)r*256 + c)*72 + 4;
            const float* w  = mw + ky*3 + kx;
#pragma unroll
            for (int ch = 0; ch < 64; ch += 4) {
                f32x4 v = *(const f32x4*)(ab + ch);
                s0 += v[0]*w[(ch+0)*9] + v[1]*w[(ch+1)*9] + v[2]*w[(ch+2)*9] + v[3]*w[(ch+3)*9];
                s1 += v[0]*w[(64+ch+0)*9] + v[1]*w[(64+ch+1)*9] + v[2]*w[(64+ch+2)*9] + v[3]*w[(64+ch+3)*9];
            }
        }
    }
    smn[px]        = s0;
    smn[NPIX + px] = s1;
}

// ---------------- fused bilinear 2x upsample (68 ch) + mask_next → d_out -----------
__global__ void k_up(const float* __restrict__ accp, const float* __restrict__ smn,
                     const float* __restrict__ sm, float* __restrict__ outp)
{
    int o = blockIdx.x*256 + threadIdx.x;
    int oy = o >> 9, ox = o & 511;
    int my = oy >> 1, mx = ox >> 1;
    int r0, r1, c0, c1; float wy0, wy1, wx0, wx1;
    if (oy & 1) { r0 = my;            r1 = min(my+1, 255); wy0 = 0.75f; wy1 = 0.25f; }
    else        { r0 = max(my-1, 0);  r1 = my;             wy0 = 0.25f; wy1 = 0.75f; }
    if (ox & 1) { c0 = mx;            c1 = min(mx+1, 255); wx0 = 0.75f; wx1 = 0.25f; }
    else        { c0 = max(mx-1, 0);  c1 = mx;             wx0 = 0.25f; wx1 = 0.75f; }
    float w00 = wy0*wx0, w01 = wy0*wx1, w10 = wy1*wx0, w11 = wy1*wx1;
    int i00 = r0*256 + c0, i01 = r0*256 + c1, i10 = r1*256 + c0, i11 = r1*256 + c1;

    const float* p00 = accp + (size_t)i00*72;
    const float* p01 = accp + (size_t)i01*72;
    const float* p10 = accp + (size_t)i10*72;
    const float* p11 = accp + (size_t)i11*72;
#pragma unroll
    for (int ch = 0; ch < 68; ch += 4) {
        f32x4 va = *(const f32x4*)(p00 + ch);
        f32x4 vb = *(const f32x4*)(p01 + ch);
        f32x4 vc = *(const f32x4*)(p10 + ch);
        f32x4 vd = *(const f32x4*)(p11 + ch);
        f32x4 v;
#pragma unroll
        for (int r = 0; r < 4; ++r)
            v[r] = w00*va[r] + w01*vb[r] + w10*vc[r] + w11*vd[r];
        outp[(size_t)(ch+0)*262144 + o] = v[0];
        outp[(size_t)(ch+1)*262144 + o] = v[1];
        outp[(size_t)(ch+2)*262144 + o] = v[2];
        outp[(size_t)(ch+3)*262144 + o] = v[3];
    }
    float s0 = w00*smn[i00] + w01*smn[i01] + w10*smn[i10] + w11*smn[i11];
    float s1 = w00*smn[NPIX+i00] + w01*smn[NPIX+i01] + w10*smn[NPIX+i10] + w11*smn[NPIX+i11];
    outp[(size_t)68*262144 + o] = (s0 > s1) ? sm[my*256 + mx] : 0.f;
}

// ---------------- launcher ----------------
extern "C" void kernel_launch(void* const* d_in, const int* in_sizes, int n_in,
                              void* d_out, int out_size, void* d_ws, size_t ws_size,
                              hipStream_t stream)
{
    const float* feat0  = (const float*)d_in[0];
    const float* feat1  = (const float*)d_in[1];
    const float* featd  = (const float*)d_in[2];
    const float* flow   = (const float*)d_in[3];
    const float* smask  = (const float*)d_in[4];
    const float* head_w = (const float*)d_in[5];
    const float* head_a = (const float*)d_in[6];
    const float* conv_w = (const float*)d_in[7];
    const float* conv_a = (const float*)d_in[8];
    const float* last_w = (const float*)d_in[9];
    const float* last_b = (const float*)d_in[10];
    const float* mask_w = (const float*)d_in[11];
    const float* mask_b = (const float*)d_in[12];
    float* outp = (float*)d_out;

    char* ws = (char*)d_ws;
    size_t off = 0;
    f16* bufA = (f16*)(ws + off); off += SBUF;
    f16* bufB = (f16*)(ws + off); off += SBUF;
    f16* packc = (f16*)(ws + off); off += (size_t)4*PK_CONV*2;
    f16* packl = (f16*)(ws + off); off += (size_t)4*PKL_BI*2;
    float* accp = (float*)(ws + off); off += (size_t)NPIX*72*4;
    float* smn  = (float*)(ws + off); off += (size_t)2*NPIX*4;

    // zero pad rows (stored rows 0 and 257) of both buffers; then halo columns
    hipMemsetAsync(bufA, 0, RBYTES, stream);
    hipMemsetAsync((char*)bufA + (size_t)257*RBYTES, 0, RBYTES, stream);
    hipMemsetAsync(bufB, 0, RBYTES, stream);
    hipMemsetAsync((char*)bufB + (size_t)257*RBYTES, 0, RBYTES, stream);
    k_zero_halo<<<226, 256, 0, stream>>>(bufA, bufB);

    // 4 layers x 1764 frags x 64 lanes = 451,584 threads (dead slices skipped inside)
    k_pack_conv<<<1764, 256, 0, stream>>>(head_w, conv_w, packc);
    k_pack_last<<<70, 256, 0, stream>>>(last_w, packl);
    k_warp_concat<<<256, 256, 0, stream>>>(feat0, feat1, featd, flow, bufA);

    // head: x0(bufA) -> bufB = outs[0]
    k_conv32<<<1024, 128, 0, stream>>>(bufA, bufB, packc, head_a, smask);
    k_acc_last<<<512, 256, 0, stream>>>(bufB, packl, last_b, accp, 0);
    // layer1: bufB -> bufA = outs[1]
    k_conv32<<<1024, 128, 0, stream>>>(bufB, bufA, packc + (size_t)1*PK_CONV, conv_a, smask);
    k_acc_last<<<512, 256, 0, stream>>>(bufA, packl, last_b, accp, 1);
    // layer2: bufA -> bufB = outs[2]
    k_conv32<<<1024, 128, 0, stream>>>(bufA, bufB, packc + (size_t)2*PK_CONV, conv_a + 196, smask);
    k_acc_last<<<512, 256, 0, stream>>>(bufB, packl, last_b, accp, 2);
    // layer3: bufB -> bufA = outs[3]
    k_conv32<<<1024, 128, 0, stream>>>(bufB, bufA, packc + (size_t)3*PK_CONV, conv_a + 392, smask);
    k_acc_last<<<512, 256, 0, stream>>>(bufA, packl, last_b, accp, 3);

    k_smn<<<256, 256, 0, stream>>>(accp, mask_w, mask_b, smn);
    k_up<<<1024, 256, 0, stream>>>(accp, smn, smask, outp);
}

// Round 18
// 784.536 us; speedup vs baseline: 1.0583x; 1.0583x over previous
//
#include <hip/hip_runtime.h>

typedef _Float16 f16;
typedef _Float16 f16x8 __attribute__((ext_vector_type(8)));
typedef _Float16 f16x4 __attribute__((ext_vector_type(4)));
typedef float    f32x4 __attribute__((ext_vector_type(4)));
typedef float    f32x16 __attribute__((ext_vector_type(16)));

#define MFMA16(a,b,c) __builtin_amdgcn_mfma_f32_16x16x32_f16(a,b,c,0,0,0)
#define MFMA32(a,b,c) __builtin_amdgcn_mfma_f32_32x32x16_f16(a,b,c,0,0,0)

#define AS1 __attribute__((address_space(1)))
#define AS3 __attribute__((address_space(3)))

#define NPIX 65536
// activation layout (halves): [row 258][cb 7][h 2][k16 2][kh 2][px 258][8]
#define PXS   8
#define KHS   2064      // 258*8
#define K16S  4128
#define HS    8256
#define CBS   16512
#define ROWH  115584    // halves per row
#define RBYTES 231168
#define SBUF  ((size_t)258*RBYTES)   // 59,641,344 B

// conv weight pack (halves): 117 LIVE slices per layer, slice = [sel 2][ob 7][lane 64][8]
// slice order: ky-major, cb, k16 (cb=6 has only k16=0), kx
#define PKSUB  7168
#define PK_CONV 903168   // per-layer stride (126 slots; tail unused)
#define NMICRO 117
#define NPAIR  59        // 58 full pairs + 1 single

// last (1x1) pack strides (halves)
#define PKL_CB  5120
#define PKL_BI  35840

#define A2STG 28672      // paired A slice bytes (2 x 14336)

// ---------------- weight packing: 3x3 convs, 32x32 A-fragment order ----------------
__global__ void k_pack_conv(const float* __restrict__ head_w,
                            const float* __restrict__ conv_w,
                            f16* __restrict__ dst)
{
    int t = blockIdx.x*256 + threadIdx.x;
    int lane = t & 63; t >>= 6;
    int ob  = t % 7;  t /= 7;
    int sel = t & 1;  t >>= 1;
    int kx  = t % 3;  t /= 3;
    int k16 = t & 1;  t >>= 1;
    int cb  = t % 7;  t /= 7;
    int ky  = t % 3;  t /= 3;
    int li  = t;
    if (li >= 4) return;
    if (cb == 6 && k16 == 1) return;          // dead slice: ic 208..223 all zero
    const float* W = (li == 0) ? head_w : (conv_w + (size_t)(li-1)*196*196*9);
    int oc  = ob*32 + (lane & 31);
    int ic0 = cb*32 + k16*16 + (lane >> 5)*8;
    int tap = ky*3 + kx;
    f16x8 v;
#pragma unroll
    for (int j = 0; j < 8; ++j) {
        int ic = ic0 + j;
        float x = 0.f;
        if (oc < 196 && ic < 196) x = W[((size_t)oc*196 + ic)*9 + tap];
        f16 h = (f16)x;
        v[j] = (sel == 0) ? h : (f16)(x - (float)h);
    }
    int pos = ky*39 + ((cb < 6) ? (cb*6 + k16*3 + kx) : (36 + kx));
    *(f16x8*)(dst + (size_t)li*PK_CONV + (size_t)pos*PKSUB
              + (size_t)(sel*7 + ob)*512 + (size_t)lane*8) = v;
}

__global__ void k_pack_last(const float* __restrict__ last_w, f16* __restrict__ dst)
{
    int t = blockIdx.x*256 + threadIdx.x;
    if (t >= 4*7*5*2*64) return;
    int lane = t & 63; t >>= 6;
    int sel  = t & 1;  t >>= 1;
    int ob   = t % 5;  t /= 5;
    int cb   = t % 7;  t /= 7;
    int bi   = t;
    int oc = ob*16 + (lane & 15);
    int k0 = cb*32 + (lane >> 4)*8;
    f16x8 v;
#pragma unroll
    for (int j = 0; j < 8; ++j) {
        int k = k0 + j;
        float x = 0.f;
        if (oc < 68 && k < 196) x = last_w[(size_t)oc*784 + bi*196 + k];
        f16 h = (f16)x;
        v[j] = (sel == 0) ? h : (f16)(x - (float)h);
    }
    *(f16x8*)(dst + (((size_t)((bi*7+cb)*5 + ob)*2 + sel)*64 + lane)*8) = v;
}

// ---------------- zero the halo px-slots (0 and 257) of every row/slice ----------------
__global__ void k_zero_halo(f16* __restrict__ bufA, f16* __restrict__ bufB)
{
    int c = blockIdx.x*256 + threadIdx.x;
    int end = c & 1; c >>= 1;
    int kh  = c & 1; c >>= 1;
    int k16 = c & 1; c >>= 1;
    int h   = c & 1; c >>= 1;
    int cb  = c % 7; c /= 7;
    int row = c % 258; c /= 258;
    if (c >= 2) return;
    f16* base = (c == 0) ? bufA : bufB;
    f16* p = base + (size_t)row*ROWH + cb*CBS + h*HS + k16*K16S + kh*KHS + (end ? 257 : 0)*PXS;
    f16x8 z = {(f16)0,(f16)0,(f16)0,(f16)0,(f16)0,(f16)0,(f16)0,(f16)0};
    *(f16x8*)p = z;
}

// ---------------- warp + concat → x0 ----------------
struct Gath { int o00,o01,o10,o11; float w00,w01,w10,w11; };

__device__ inline Gath mk_gath(float pxf, float pyf)
{
    float x0 = floorf(pxf), y0 = floorf(pyf);
    float x1 = x0 + 1.f, y1 = y0 + 1.f;
    float wx1 = pxf - x0, wx0 = 1.f - wx1;
    float wy1 = pyf - y0, wy0 = 1.f - wy1;
    bool vx0 = (x0 >= 0.f) && (x0 <= 255.f);
    bool vx1 = (x1 >= 0.f) && (x1 <= 255.f);
    bool vy0 = (y0 >= 0.f) && (y0 <= 255.f);
    bool vy1 = (y1 >= 0.f) && (y1 <= 255.f);
    int ix0 = min(max((int)x0, 0), 255);
    int ix1 = min(max((int)x1, 0), 255);
    int iy0 = min(max((int)y0, 0), 255);
    int iy1 = min(max((int)y1, 0), 255);
    Gath g;
    g.o00 = iy0*256 + ix0; g.w00 = (vx0 && vy0) ? wx0*wy0 : 0.f;
    g.o01 = iy0*256 + ix1; g.w01 = (vx1 && vy0) ? wx1*wy0 : 0.f;
    g.o10 = iy1*256 + ix0; g.w10 = (vx0 && vy1) ? wx0*wy1 : 0.f;
    g.o11 = iy1*256 + ix1; g.w11 = (vx1 && vy1) ? wx1*wy1 : 0.f;
    return g;
}

__device__ inline void store4n(f16* __restrict__ rowb, int slot, int c0,
                               float a, float b, float c, float d)
{
    f16x4 hi, lo;
    f16 h;
    h = (f16)a; hi[0] = h; lo[0] = (f16)(a - (float)h);
    h = (f16)b; hi[1] = h; lo[1] = (f16)(b - (float)h);
    h = (f16)c; hi[2] = h; lo[2] = (f16)(c - (float)h);
    h = (f16)d; hi[3] = h; lo[3] = (f16)(d - (float)h);
    int cb = c0 >> 5, w32 = c0 & 31;
    f16* p = rowb + cb*CBS + (w32 >> 4)*K16S + ((w32 >> 3) & 1)*KHS
                 + (size_t)slot*PXS + (w32 & 7);
    *(f16x4*)p        = hi;
    *(f16x4*)(p + HS) = lo;
}

__global__ void k_warp_concat(const float* __restrict__ f0, const float* __restrict__ f1,
                              const float* __restrict__ fd, const float* __restrict__ flow,
                              f16* __restrict__ out)
{
    int px = blockIdx.x*256 + threadIdx.x;
    int row = px >> 8, col = px & 255;
    f16* rowb = out + (size_t)(row+1)*ROWH;
    int slot = col + 1;
    Gath g0 = mk_gath((float)col + flow[px],          (float)row + flow[NPIX   + px]);
    Gath g1 = mk_gath((float)col + flow[2*NPIX + px], (float)row + flow[3*NPIX + px]);
#pragma unroll
    for (int c = 0; c < 64; c += 4) {
        float v[4];
#pragma unroll
        for (int r = 0; r < 4; ++r) {
            const float* im = f0 + (size_t)(c+r)*NPIX;
            v[r] = g0.w00*im[g0.o00] + g0.w01*im[g0.o01] + g0.w10*im[g0.o10] + g0.w11*im[g0.o11];
        }
        store4n(rowb, slot, c, v[0], v[1], v[2], v[3]);
    }
#pragma unroll
    for (int c = 0; c < 64; c += 4) {
        float v[4];
#pragma unroll
        for (int r = 0; r < 4; ++r) {
            const float* im = f1 + (size_t)(c+r)*NPIX;
            v[r] = g1.w00*im[g1.o00] + g1.w01*im[g1.o01] + g1.w10*im[g1.o10] + g1.w11*im[g1.o11];
        }
        store4n(rowb, slot, 64 + c, v[0], v[1], v[2], v[3]);
    }
#pragma unroll
    for (int c = 0; c < 64; c += 4) {
        store4n(rowb, slot, 128 + c, fd[(size_t)(c+0)*NPIX + px], fd[(size_t)(c+1)*NPIX + px],
                                     fd[(size_t)(c+2)*NPIX + px], fd[(size_t)(c+3)*NPIX + px]);
    }
    store4n(rowb, slot, 192, flow[px], flow[NPIX+px], flow[2*NPIX+px], flow[3*NPIX+px]);
#pragma unroll
    for (int c = 196; c < 224; c += 4) store4n(rowb, slot, c, 0.f, 0.f, 0.f, 0.f);
}

// ---------------- 3x3 conv: R15 body with PAIRED micros (59 barriers) --------------
// 512 blocks x 256 thr (4 waves). Wave = ALL 7 ob32 x one 32-px tile.
// Per phase: stage next PAIR of A slices (28KB dbuf) + prefetch both B pairs;
// two sub-micros back-to-back (no barrier between — their ds_reads/MFMAs overlap);
// one __syncthreads per phase.
__global__ __launch_bounds__(256, 2)
void k_conv32(const f16* __restrict__ in, f16* __restrict__ out,
              const f16* __restrict__ pack, const float* __restrict__ alpha,
              const float* __restrict__ mask)
{
    __shared__ __align__(16) char As[2][A2STG];

    int bid = blockIdx.x;
    int wg  = (bid & 7)*64 + (bid >> 3);      // bijective XCD swizzle (512 % 8 == 0)
    int row  = wg >> 1;
    int half = wg & 1;
    int tid  = threadIdx.x;
    int lane = tid & 63;
    int w    = tid >> 6;
    int pxt  = half*4 + w;
    int l31 = lane & 31, lk = lane >> 5;

    f32x16 acc[7];
#pragma unroll
    for (int o = 0; o < 7; ++o)
#pragma unroll
        for (int e = 0; e < 16; ++e) acc[o][e] = 0.f;

    // stage a PAIR of A slices (1792 x 16B chunks = exactly 7 DMA/thread)
    auto stage2 = [&](int b, const f16* src) {
#pragma unroll
        for (int u = 0; u < 7; ++u) {
            int c = tid + u*256;
            __builtin_amdgcn_global_load_lds(
                (const AS1 void*)(src + (size_t)c*8),
                (AS3 void*)(&As[b][0] + c*16), 16, 0, 0);
        }
    };

    // B address for micro q (q -> ky, cb, k16, kx per pack order)
    auto baddr = [&](int q) -> const f16* {
        int ky = q / 39;
        int r  = q - ky*39;
        int cb, k16, kx;
        if (r < 36) { cb = r/6; int s = r - cb*6; k16 = s/3; kx = s - k16*3; }
        else        { cb = 6; k16 = 0; kx = r - 36; }
        return in + (size_t)(row+ky)*ROWH + cb*CBS + k16*K16S + (size_t)lk*KHS
                  + (size_t)(pxt*32 + l31 + kx)*PXS;
    };

    auto lB = [&](const f16* bp, f16x8& H, f16x8& L) {
        H = *(const f16x8*)bp;
        L = *(const f16x8*)(bp + HS);
    };

    f16x8 Bh[2], Bl[2], Bnh[2], Bnl[2];
    stage2(0, pack);
    lB(baddr(0), Bh[0], Bl[0]);
    lB(baddr(1), Bh[1], Bl[1]);
    __syncthreads();

    int bsel = 0;
    for (int p = 0; p < NPAIR; ++p) {
        int q0 = 2*p;
        bool lastPair = (p == NPAIR - 1);     // q0 = 116, single micro
        if (!lastPair) {
            stage2(bsel ^ 1, pack + (size_t)(q0+2)*PKSUB);
            lB(baddr(q0+2), Bnh[0], Bnl[0]);
            if (q0 + 3 < NMICRO) lB(baddr(q0+3), Bnh[1], Bnl[1]);
        }
        const char* ab = &As[bsel][0];
        __builtin_amdgcn_s_setprio(1);
#pragma unroll
        for (int o = 0; o < 7; ++o) {
            f16x8 Ah = *(const f16x8*)(ab + o*1024 + lane*16);
            f16x8 Al = *(const f16x8*)(ab + (7+o)*1024 + lane*16);
            acc[o] = MFMA32(Ah, Bh[0], acc[o]);
            acc[o] = MFMA32(Al, Bh[0], acc[o]);
            acc[o] = MFMA32(Ah, Bl[0], acc[o]);
        }
        if (!lastPair) {
#pragma unroll
            for (int o = 0; o < 7; ++o) {
                f16x8 Ah = *(const f16x8*)(ab + 14336 + o*1024 + lane*16);
                f16x8 Al = *(const f16x8*)(ab + 14336 + (7+o)*1024 + lane*16);
                acc[o] = MFMA32(Ah, Bh[1], acc[o]);
                acc[o] = MFMA32(Al, Bh[1], acc[o]);
                acc[o] = MFMA32(Ah, Bl[1], acc[o]);
            }
        }
        __builtin_amdgcn_s_setprio(0);
        __syncthreads();
        bsel ^= 1;
#pragma unroll
        for (int t2 = 0; t2 < 2; ++t2) { Bh[t2] = Bnh[t2]; Bl[t2] = Bnl[t2]; }
    }

    // epilogue: prelu * mask, split-f16 store into the channel-major layout
    float mv = mask[row*256 + pxt*32 + l31];
    f16* orow = out + (size_t)(row+1)*ROWH + (size_t)(pxt*32 + l31 + 1)*PXS + lk*4;
#pragma unroll
    for (int o = 0; o < 7; ++o) {
#pragma unroll
        for (int qg = 0; qg < 4; ++qg) {
            int oc0 = o*32 + 8*qg + 4*lk;
            f32x4 a4 = *(const f32x4*)(alpha + min(oc0, 192));
            f16x4 hi, lo;
#pragma unroll
            for (int e = 0; e < 4; ++e) {
                float v = acc[o][qg*4 + e];
                v = (v >= 0.f ? v : a4[e]*v) * mv;
                f16 h = (f16)v;
                hi[e] = h;
                lo[e] = (f16)(v - (float)h);
            }
            f16* p = orow + o*CBS + (qg >> 1)*K16S + (qg & 1)*KHS;
            *(f16x4*)p        = hi;
            *(f16x4*)(p + HS) = lo;
        }
    }
}

// ---------------- incremental 1x1 last-conv: acc[px][72] (+= / init with bias) ----------------
__global__ __launch_bounds__(256, 4)
void k_acc_last(const f16* __restrict__ in, const f16* __restrict__ pack,
                const float* __restrict__ bias, float* __restrict__ accp, int bi)
{
    int lane = threadIdx.x & 63;
    int wid  = (blockIdx.x << 2) | (threadIdx.x >> 6);
    int row  = wid >> 3;
    int col0 = (wid & 7) << 5;
    int l15 = lane & 15, lk = lane >> 4;

    f32x4 acc[5][2];
#pragma unroll
    for (int i = 0; i < 5; ++i)
#pragma unroll
        for (int j = 0; j < 2; ++j)
            acc[i][j] = (f32x4){0.f, 0.f, 0.f, 0.f};

    const f16* bb = in + (size_t)(row+1)*ROWH + (size_t)(col0 + l15 + 1)*PXS
                  + (lk >> 1)*K16S + (lk & 1)*KHS;
    const f16* ap = pack + (size_t)bi*PKL_BI + (size_t)lane*8;
    for (int cb = 0; cb < 7; ++cb) {
        f16x8 bh[2], bl[2];
#pragma unroll
        for (int pb = 0; pb < 2; ++pb) {
            const f16* p = bb + cb*CBS + pb*16*PXS;
            bh[pb] = *(const f16x8*)p;
            bl[pb] = *(const f16x8*)(p + HS);
        }
        const f16* a = ap + cb*PKL_CB;
#pragma unroll
        for (int ob = 0; ob < 5; ++ob) {
            f16x8 ah = *(const f16x8*)(a + ob*1024);
            f16x8 al = *(const f16x8*)(a + ob*1024 + 512);
#pragma unroll
            for (int pb = 0; pb < 2; ++pb) {
                acc[ob][pb] = MFMA16(ah, bh[pb], acc[ob][pb]);
                acc[ob][pb] = MFMA16(ah, bl[pb], acc[ob][pb]);
                acc[ob][pb] = MFMA16(al, bh[pb], acc[ob][pb]);
            }
        }
    }
#pragma unroll
    for (int ob = 0; ob < 5; ++ob) {
        int oc0 = ob*16 + lk*4;
        if (oc0 >= 72) continue;           // accp stride is 72 floats
#pragma unroll
        for (int pb = 0; pb < 2; ++pb) {
            int px = row*256 + col0 + pb*16 + l15;
            float* dst = accp + (size_t)px*72 + oc0;
            f32x4 d = acc[ob][pb];
            if (bi == 0) {
                f32x4 b4;
#pragma unroll
                for (int r = 0; r < 4; ++r) b4[r] = bias[min(oc0 + r, 67)];
                *(f32x4*)dst = d + b4;
            } else {
                *(f32x4*)dst = *(const f32x4*)dst + d;
            }
        }
    }
}

// ---------------- smn = 3x3 conv(acc[4:68]) + mask_b  (plain f32) ----------------
__global__ void k_smn(const float* __restrict__ accp, const float* __restrict__ mw,
                      const float* __restrict__ mb, float* __restrict__ smn)
{
    int px = blockIdx.x*256 + threadIdx.x;
    int row = px >> 8, col = px & 255;
    float s0 = mb[0], s1 = mb[1];
    for (int ky = 0; ky < 3; ++ky) {
        int r = row + ky - 1;
        if ((unsigned)r > 255u) continue;
        for (int kx = 0; kx < 3; ++kx) {
            int c = col + kx - 1;
            if ((unsigned)c > 255u) continue;
            const float* ab = accp + ((size_t)r*256 + c)*72 + 4;
            const float* w  = mw + ky*3 + kx;
#pragma unroll
            for (int ch = 0; ch < 64; ch += 4) {
                f32x4 v = *(const f32x4*)(ab + ch);
                s0 += v[0]*w[(ch+0)*9] + v[1]*w[(ch+1)*9] + v[2]*w[(ch+2)*9] + v[3]*w[(ch+3)*9];
                s1 += v[0]*w[(64+ch+0)*9] + v[1]*w[(64+ch+1)*9] + v[2]*w[(64+ch+2)*9] + v[3]*w[(64+ch+3)*9];
            }
        }
    }
    smn[px]        = s0;
    smn[NPIX + px] = s1;
}

// ---------------- fused bilinear 2x upsample (68 ch) + mask_next → d_out -----------
__global__ void k_up(const float* __restrict__ accp, const float* __restrict__ smn,
                     const float* __restrict__ sm, float* __restrict__ outp)
{
    int o = blockIdx.x*256 + threadIdx.x;
    int oy = o >> 9, ox = o & 511;
    int my = oy >> 1, mx = ox >> 1;
    int r0, r1, c0, c1; float wy0, wy1, wx0, wx1;
    if (oy & 1) { r0 = my;            r1 = min(my+1, 255); wy0 = 0.75f; wy1 = 0.25f; }
    else        { r0 = max(my-1, 0);  r1 = my;             wy0 = 0.25f; wy1 = 0.75f; }
    if (ox & 1) { c0 = mx;            c1 = min(mx+1, 255); wx0 = 0.75f; wx1 = 0.25f; }
    else        { c0 = max(mx-1, 0);  c1 = mx;             wx0 = 0.25f; wx1 = 0.75f; }
    float w00 = wy0*wx0, w01 = wy0*wx1, w10 = wy1*wx0, w11 = wy1*wx1;
    int i00 = r0*256 + c0, i01 = r0*256 + c1, i10 = r1*256 + c0, i11 = r1*256 + c1;

    const float* p00 = accp + (size_t)i00*72;
    const float* p01 = accp + (size_t)i01*72;
    const float* p10 = accp + (size_t)i10*72;
    const float* p11 = accp + (size_t)i11*72;
#pragma unroll
    for (int ch = 0; ch < 68; ch += 4) {
        f32x4 va = *(const f32x4*)(p00 + ch);
        f32x4 vb = *(const f32x4*)(p01 + ch);
        f32x4 vc = *(const f32x4*)(p10 + ch);
        f32x4 vd = *(const f32x4*)(p11 + ch);
        f32x4 v;
#pragma unroll
        for (int r = 0; r < 4; ++r)
            v[r] = w00*va[r] + w01*vb[r] + w10*vc[r] + w11*vd[r];
        outp[(size_t)(ch+0)*262144 + o] = v[0];
        outp[(size_t)(ch+1)*262144 + o] = v[1];
        outp[(size_t)(ch+2)*262144 + o] = v[2];
        outp[(size_t)(ch+3)*262144 + o] = v[3];
    }
    float s0 = w00*smn[i00] + w01*smn[i01] + w10*smn[i10] + w11*smn[i11];
    float s1 = w00*smn[NPIX+i00] + w01*smn[NPIX+i01] + w10*smn[NPIX+i10] + w11*smn[NPIX+i11];
    outp[(size_t)68*262144 + o] = (s0 > s1) ? sm[my*256 + mx] : 0.f;
}

// ---------------- launcher ----------------
extern "C" void kernel_launch(void* const* d_in, const int* in_sizes, int n_in,
                              void* d_out, int out_size, void* d_ws, size_t ws_size,
                              hipStream_t stream)
{
    const float* feat0  = (const float*)d_in[0];
    const float* feat1  = (const float*)d_in[1];
    const float* featd  = (const float*)d_in[2];
    const float* flow   = (const float*)d_in[3];
    const float* smask  = (const float*)d_in[4];
    const float* head_w = (const float*)d_in[5];
    const float* head_a = (const float*)d_in[6];
    const float* conv_w = (const float*)d_in[7];
    const float* conv_a = (const float*)d_in[8];
    const float* last_w = (const float*)d_in[9];
    const float* last_b = (const float*)d_in[10];
    const float* mask_w = (const float*)d_in[11];
    const float* mask_b = (const float*)d_in[12];
    float* outp = (float*)d_out;

    char* ws = (char*)d_ws;
    size_t off = 0;
    f16* bufA = (f16*)(ws + off); off += SBUF;
    f16* bufB = (f16*)(ws + off); off += SBUF;
    f16* packc = (f16*)(ws + off); off += (size_t)4*PK_CONV*2;
    f16* packl = (f16*)(ws + off); off += (size_t)4*PKL_BI*2;
    float* accp = (float*)(ws + off); off += (size_t)NPIX*72*4;
    float* smn  = (float*)(ws + off); off += (size_t)2*NPIX*4;

    // zero pad rows (stored rows 0 and 257) of both buffers; then halo columns
    hipMemsetAsync(bufA, 0, RBYTES, stream);
    hipMemsetAsync((char*)bufA + (size_t)257*RBYTES, 0, RBYTES, stream);
    hipMemsetAsync(bufB, 0, RBYTES, stream);
    hipMemsetAsync((char*)bufB + (size_t)257*RBYTES, 0, RBYTES, stream);
    k_zero_halo<<<226, 256, 0, stream>>>(bufA, bufB);

    // 4 layers x 1764 frags x 64 lanes = 451,584 threads (dead slices skipped inside)
    k_pack_conv<<<1764, 256, 0, stream>>>(head_w, conv_w, packc);
    k_pack_last<<<70, 256, 0, stream>>>(last_w, packl);
    k_warp_concat<<<256, 256, 0, stream>>>(feat0, feat1, featd, flow, bufA);

    // head: x0(bufA) -> bufB = outs[0]
    k_conv32<<<512, 256, 0, stream>>>(bufA, bufB, packc, head_a, smask);
    k_acc_last<<<512, 256, 0, stream>>>(bufB, packl, last_b, accp, 0);
    // layer1: bufB -> bufA = outs[1]
    k_conv32<<<512, 256, 0, stream>>>(bufB, bufA, packc + (size_t)1*PK_CONV, conv_a, smask);
    k_acc_last<<<512, 256, 0, stream>>>(bufA, packl, last_b, accp, 1);
    // layer2: bufA -> bufB = outs[2]
    k_conv32<<<512, 256, 0, stream>>>(bufA, bufB, packc + (size_t)2*PK_CONV, conv_a + 196, smask);
    k_acc_last<<<512, 256, 0, stream>>>(bufB, packl, last_b, accp, 2);
    // layer3: bufB -> bufA = outs[3]
    k_conv32<<<512, 256, 0, stream>>>(bufB, bufA, packc + (size_t)3*PK_CONV, conv_a + 392, smask);
    k_acc_last<<<512, 256, 0, stream>>>(bufA, packl, last_b, accp, 3);

    k_smn<<<256, 256, 0, stream>>>(accp, mask_w, mask_b, smn);
    k_up<<<1024, 256, 0, stream>>>(accp, smn, smask, outp);
}

// Round 19
// 743.015 us; speedup vs baseline: 1.1174x; 1.0559x over previous
//
#include <hip/hip_runtime.h>

typedef _Float16 f16;
typedef _Float16 f16x8 __attribute__((ext_vector_type(8)));
typedef _Float16 f16x4 __attribute__((ext_vector_type(4)));
typedef float    f32x4 __attribute__((ext_vector_type(4)));
typedef float    f32x16 __attribute__((ext_vector_type(16)));

#define MFMA16(a,b,c) __builtin_amdgcn_mfma_f32_16x16x32_f16(a,b,c,0,0,0)
#define MFMA32(a,b,c) __builtin_amdgcn_mfma_f32_32x32x16_f16(a,b,c,0,0,0)

#define AS1 __attribute__((address_space(1)))
#define AS3 __attribute__((address_space(3)))

#define NPIX 65536
// activation layout (halves): [row 258][cb 7][h 2][k16 2][kh 2][px 258][8]
#define PXS   8
#define KHS   2064      // 258*8
#define K16S  4128
#define HS    8256
#define CBS   16512
#define ROWH  115584    // halves per row
#define RBYTES 231168
#define SBUF  ((size_t)258*RBYTES)   // 59,641,344 B

// conv weight pack (halves): 117 LIVE slices per layer, slice = [sel 2][ob 7][lane 64][8]
#define PKSUB  7168
#define PK_CONV 903168   // per-layer stride (126 slots; tail unused)
#define NMICRO 117

// last (1x1) pack, 16x16 layout (standalone bi=3 acc_last)
#define PKL_CB  5120
#define PKL_BI  35840
// last (1x1) pack, 32x32 layout (fused): [bi 4][s 13][sel 2][ob 3][lane 64][8]
#define PK1_S   3072     // halves per slice: 2*3*512
#define PK1_BI  39936    // 13*3072

#define ASTG 14336

// ---------------- weight packing: 3x3 convs, 32x32 A-fragment order ----------------
__global__ void k_pack_conv(const float* __restrict__ head_w,
                            const float* __restrict__ conv_w,
                            f16* __restrict__ dst)
{
    int t = blockIdx.x*256 + threadIdx.x;
    int lane = t & 63; t >>= 6;
    int ob  = t % 7;  t /= 7;
    int sel = t & 1;  t >>= 1;
    int kx  = t % 3;  t /= 3;
    int k16 = t & 1;  t >>= 1;
    int cb  = t % 7;  t /= 7;
    int ky  = t % 3;  t /= 3;
    int li  = t;
    if (li >= 4) return;
    if (cb == 6 && k16 == 1) return;          // dead slice: ic 208..223 all zero
    const float* W = (li == 0) ? head_w : (conv_w + (size_t)(li-1)*196*196*9);
    int oc  = ob*32 + (lane & 31);
    int ic0 = cb*32 + k16*16 + (lane >> 5)*8;
    int tap = ky*3 + kx;
    f16x8 v;
#pragma unroll
    for (int j = 0; j < 8; ++j) {
        int ic = ic0 + j;
        float x = 0.f;
        if (oc < 196 && ic < 196) x = W[((size_t)oc*196 + ic)*9 + tap];
        f16 h = (f16)x;
        v[j] = (sel == 0) ? h : (f16)(x - (float)h);
    }
    int pos = ky*39 + ((cb < 6) ? (cb*6 + k16*3 + kx) : (36 + kx));
    *(f16x8*)(dst + (size_t)li*PK_CONV + (size_t)pos*PKSUB
              + (size_t)(sel*7 + ob)*512 + (size_t)lane*8) = v;
}

// 1x1 weights in 16x16 A-frag order (standalone bi=3 pass)
__global__ void k_pack_last(const float* __restrict__ last_w, f16* __restrict__ dst)
{
    int t = blockIdx.x*256 + threadIdx.x;
    if (t >= 4*7*5*2*64) return;
    int lane = t & 63; t >>= 6;
    int sel  = t & 1;  t >>= 1;
    int ob   = t % 5;  t /= 5;
    int cb   = t % 7;  t /= 7;
    int bi   = t;
    int oc = ob*16 + (lane & 15);
    int k0 = cb*32 + (lane >> 4)*8;
    f16x8 v;
#pragma unroll
    for (int j = 0; j < 8; ++j) {
        int k = k0 + j;
        float x = 0.f;
        if (oc < 68 && k < 196) x = last_w[(size_t)oc*784 + bi*196 + k];
        f16 h = (f16)x;
        v[j] = (sel == 0) ? h : (f16)(x - (float)h);
    }
    *(f16x8*)(dst + (((size_t)((bi*7+cb)*5 + ob)*2 + sel)*64 + lane)*8) = v;
}

// 1x1 weights in 32x32 A-frag order (fused into conv center-tap micros)
__global__ void k_pack_last32(const float* __restrict__ last_w, f16* __restrict__ dst)
{
    int t = blockIdx.x*256 + threadIdx.x;
    if (t >= 4*13*2*3*64) return;
    int lane = t & 63; t >>= 6;
    int ob   = t % 3;  t /= 3;
    int sel  = t & 1;  t >>= 1;
    int s    = t % 13; t /= 13;
    int bi   = t;
    int cb  = (s < 12) ? (s >> 1) : 6;
    int k16 = (s < 12) ? (s & 1)  : 0;
    int oc  = ob*32 + (lane & 31);
    int ic0 = cb*32 + k16*16 + (lane >> 5)*8;
    f16x8 v;
#pragma unroll
    for (int j = 0; j < 8; ++j) {
        int ic = ic0 + j;
        float x = 0.f;
        if (oc < 68 && ic < 196) x = last_w[(size_t)oc*784 + bi*196 + ic];
        f16 h = (f16)x;
        v[j] = (sel == 0) ? h : (f16)(x - (float)h);
    }
    *(f16x8*)(dst + (size_t)bi*PK1_BI + (size_t)s*PK1_S
              + (size_t)(sel*3 + ob)*512 + (size_t)lane*8) = v;
}

// ---------------- zero the halo px-slots (0 and 257) of every row/slice ----------------
__global__ void k_zero_halo(f16* __restrict__ bufA, f16* __restrict__ bufB)
{
    int c = blockIdx.x*256 + threadIdx.x;
    int end = c & 1; c >>= 1;
    int kh  = c & 1; c >>= 1;
    int k16 = c & 1; c >>= 1;
    int h   = c & 1; c >>= 1;
    int cb  = c % 7; c /= 7;
    int row = c % 258; c /= 258;
    if (c >= 2) return;
    f16* base = (c == 0) ? bufA : bufB;
    f16* p = base + (size_t)row*ROWH + cb*CBS + h*HS + k16*K16S + kh*KHS + (end ? 257 : 0)*PXS;
    f16x8 z = {(f16)0,(f16)0,(f16)0,(f16)0,(f16)0,(f16)0,(f16)0,(f16)0};
    *(f16x8*)p = z;
}

// ---------------- warp + concat → x0 ----------------
struct Gath { int o00,o01,o10,o11; float w00,w01,w10,w11; };

__device__ inline Gath mk_gath(float pxf, float pyf)
{
    float x0 = floorf(pxf), y0 = floorf(pyf);
    float x1 = x0 + 1.f, y1 = y0 + 1.f;
    float wx1 = pxf - x0, wx0 = 1.f - wx1;
    float wy1 = pyf - y0, wy0 = 1.f - wy1;
    bool vx0 = (x0 >= 0.f) && (x0 <= 255.f);
    bool vx1 = (x1 >= 0.f) && (x1 <= 255.f);
    bool vy0 = (y0 >= 0.f) && (y0 <= 255.f);
    bool vy1 = (y1 >= 0.f) && (y1 <= 255.f);
    int ix0 = min(max((int)x0, 0), 255);
    int ix1 = min(max((int)x1, 0), 255);
    int iy0 = min(max((int)y0, 0), 255);
    int iy1 = min(max((int)y1, 0), 255);
    Gath g;
    g.o00 = iy0*256 + ix0; g.w00 = (vx0 && vy0) ? wx0*wy0 : 0.f;
    g.o01 = iy0*256 + ix1; g.w01 = (vx1 && vy0) ? wx1*wy0 : 0.f;
    g.o10 = iy1*256 + ix0; g.w10 = (vx0 && vy1) ? wx0*wy1 : 0.f;
    g.o11 = iy1*256 + ix1; g.w11 = (vx1 && vy1) ? wx1*wy1 : 0.f;
    return g;
}

__device__ inline void store4n(f16* __restrict__ rowb, int slot, int c0,
                               float a, float b, float c, float d)
{
    f16x4 hi, lo;
    f16 h;
    h = (f16)a; hi[0] = h; lo[0] = (f16)(a - (float)h);
    h = (f16)b; hi[1] = h; lo[1] = (f16)(b - (float)h);
    h = (f16)c; hi[2] = h; lo[2] = (f16)(c - (float)h);
    h = (f16)d; hi[3] = h; lo[3] = (f16)(d - (float)h);
    int cb = c0 >> 5, w32 = c0 & 31;
    f16* p = rowb + cb*CBS + (w32 >> 4)*K16S + ((w32 >> 3) & 1)*KHS
                 + (size_t)slot*PXS + (w32 & 7);
    *(f16x4*)p        = hi;
    *(f16x4*)(p + HS) = lo;
}

__global__ void k_warp_concat(const float* __restrict__ f0, const float* __restrict__ f1,
                              const float* __restrict__ fd, const float* __restrict__ flow,
                              f16* __restrict__ out)
{
    int px = blockIdx.x*256 + threadIdx.x;
    int row = px >> 8, col = px & 255;
    f16* rowb = out + (size_t)(row+1)*ROWH;
    int slot = col + 1;
    Gath g0 = mk_gath((float)col + flow[px],          (float)row + flow[NPIX   + px]);
    Gath g1 = mk_gath((float)col + flow[2*NPIX + px], (float)row + flow[3*NPIX + px]);
#pragma unroll
    for (int c = 0; c < 64; c += 4) {
        float v[4];
#pragma unroll
        for (int r = 0; r < 4; ++r) {
            const float* im = f0 + (size_t)(c+r)*NPIX;
            v[r] = g0.w00*im[g0.o00] + g0.w01*im[g0.o01] + g0.w10*im[g0.o10] + g0.w11*im[g0.o11];
        }
        store4n(rowb, slot, c, v[0], v[1], v[2], v[3]);
    }
#pragma unroll
    for (int c = 0; c < 64; c += 4) {
        float v[4];
#pragma unroll
        for (int r = 0; r < 4; ++r) {
            const float* im = f1 + (size_t)(c+r)*NPIX;
            v[r] = g1.w00*im[g1.o00] + g1.w01*im[g1.o01] + g1.w10*im[g1.o10] + g1.w11*im[g1.o11];
        }
        store4n(rowb, slot, 64 + c, v[0], v[1], v[2], v[3]);
    }
#pragma unroll
    for (int c = 0; c < 64; c += 4) {
        store4n(rowb, slot, 128 + c, fd[(size_t)(c+0)*NPIX + px], fd[(size_t)(c+1)*NPIX + px],
                                     fd[(size_t)(c+2)*NPIX + px], fd[(size_t)(c+3)*NPIX + px]);
    }
    store4n(rowb, slot, 192, flow[px], flow[NPIX+px], flow[2*NPIX+px], flow[3*NPIX+px]);
#pragma unroll
    for (int c = 196; c < 224; c += 4) store4n(rowb, slot, c, 0.f, 0.f, 0.f, 0.f);
}

// ---------------- 3x3 conv (R15 structure) + fused 1x1 at center-tap micros --------
// 512 blocks x 256 thr (4 waves). Wave = ALL 7 ob32 x one 32-px tile. 117 micros.
// At (ky==1, kx==1) micros the B regs hold x_in[px, ic-slice] — accumulate the 1x1
// (acc_last) into 3 extra 32x32 acc tiles using 32x32-packed last_w (bi = bi1).
// bi1 < 0: no fusion (head conv). bi1 == 0 also adds bias on store.
__global__ __launch_bounds__(256, 2)
void k_conv32(const f16* __restrict__ in, f16* __restrict__ out,
              const f16* __restrict__ pack, const float* __restrict__ alpha,
              const float* __restrict__ mask, const f16* __restrict__ pk1,
              const float* __restrict__ bias1, float* __restrict__ accp, int bi1)
{
    __shared__ __align__(16) char As[2][ASTG];

    int bid = blockIdx.x;
    int wg  = (bid & 7)*64 + (bid >> 3);      // bijective XCD swizzle (512 % 8 == 0)
    int row  = wg >> 1;
    int half = wg & 1;
    int tid  = threadIdx.x;
    int lane = tid & 63;
    int w    = tid >> 6;
    int pxt  = half*4 + w;
    int l31 = lane & 31, lk = lane >> 5;

    f32x16 acc[7];
#pragma unroll
    for (int o = 0; o < 7; ++o)
#pragma unroll
        for (int e = 0; e < 16; ++e) acc[o][e] = 0.f;
    f32x16 acc1[3];
#pragma unroll
    for (int o = 0; o < 3; ++o)
#pragma unroll
        for (int e = 0; e < 16; ++e) acc1[o][e] = 0.f;

    // stage A slice (896 x 16B chunks), linear both sides
    auto stage = [&](int b, const f16* src) {
        __builtin_amdgcn_global_load_lds(
            (const AS1 void*)(src + (size_t)tid*8),
            (AS3 void*)(&As[b][0] + tid*16), 16, 0, 0);
        __builtin_amdgcn_global_load_lds(
            (const AS1 void*)(src + (size_t)(tid+256)*8),
            (AS3 void*)(&As[b][0] + (tid+256)*16), 16, 0, 0);
        __builtin_amdgcn_global_load_lds(
            (const AS1 void*)(src + (size_t)(tid+512)*8),
            (AS3 void*)(&As[b][0] + (tid+512)*16), 16, 0, 0);
        if (tid < 128)
            __builtin_amdgcn_global_load_lds(
                (const AS1 void*)(src + (size_t)(tid+768)*8),
                (AS3 void*)(&As[b][0] + (tid+768)*16), 16, 0, 0);
    };

    auto lB = [&](const f16* bp, f16x8& H, f16x8& L) {
        H = *(const f16x8*)bp;
        L = *(const f16x8*)(bp + HS);
    };

    // B base: stored slot = pxt*32 + l31 + kx (halo handles the kx-1 shift)
    const f16* bcol = in + (size_t)lk*KHS + (size_t)(pxt*32 + l31)*PXS;

    f16x8 Bh0, Bl0, Bh1, Bl1;
    stage(0, pack);
    lB(bcol + (size_t)row*ROWH, Bh0, Bl0);
    __syncthreads();

    int bsel = 0, q = 0;
    for (int ky = 0; ky < 3; ++ky) {
        const f16* brow = bcol + (size_t)(row + ky)*ROWH;
        for (int cb = 0; cb < 7; ++cb) {
            const f16* bcb = brow + cb*CBS;
            const f16* bnext = (cb < 6) ? (bcb + CBS) : (brow + ROWH);
            int nk16 = (cb == 6) ? 1 : 2;
            for (int k16 = 0; k16 < 2; ++k16) {
                if (k16 >= nk16) break;
#pragma unroll
                for (int kx = 0; kx < 3; ++kx) {
                    bool last = (q == NMICRO - 1);
                    if (!last) {
                        stage(bsel ^ 1, pack + (size_t)(q+1)*PKSUB);
                        const f16* nb;
                        if (kx < 2)                  nb = bcb + k16*K16S + (kx+1)*PXS;
                        else if (k16 == 0 && cb < 6) nb = bcb + K16S;
                        else                         nb = bnext;
                        lB(nb, Bh1, Bl1);
                    }
                    // fused 1x1: load its A-frags early (L2-hot, hidden under MFMAs)
                    bool ctr = (ky == 1) && (kx == 1) && (bi1 >= 0);
                    f16x8 A1h[3], A1l[3];
                    if (ctr) {
                        int s = (cb < 6) ? (cb*2 + k16) : 12;
                        const f16* a1 = pk1 + (size_t)bi1*PK1_BI + (size_t)s*PK1_S
                                      + (size_t)lane*8;
#pragma unroll
                        for (int o = 0; o < 3; ++o) {
                            A1h[o] = *(const f16x8*)(a1 + o*512);
                            A1l[o] = *(const f16x8*)(a1 + (3+o)*512);
                        }
                    }
                    const char* ab = &As[bsel][0];
                    __builtin_amdgcn_s_setprio(1);
#pragma unroll
                    for (int o = 0; o < 7; ++o) {
                        f16x8 Ah = *(const f16x8*)(ab + o*1024 + lane*16);
                        f16x8 Al = *(const f16x8*)(ab + (7+o)*1024 + lane*16);
                        acc[o] = MFMA32(Ah, Bh0, acc[o]);
                        acc[o] = MFMA32(Al, Bh0, acc[o]);
                        acc[o] = MFMA32(Ah, Bl0, acc[o]);
                    }
                    if (ctr) {
#pragma unroll
                        for (int o = 0; o < 3; ++o) {
                            acc1[o] = MFMA32(A1h[o], Bh0, acc1[o]);
                            acc1[o] = MFMA32(A1l[o], Bh0, acc1[o]);
                            acc1[o] = MFMA32(A1h[o], Bl0, acc1[o]);
                        }
                    }
                    __builtin_amdgcn_s_setprio(0);
                    __syncthreads();
                    bsel ^= 1; ++q;
                    Bh0 = Bh1; Bl0 = Bl1;
                }
            }
        }
    }

    // epilogue: prelu * mask, split-f16 store into the channel-major layout
    float mv = mask[row*256 + pxt*32 + l31];
    f16* orow = out + (size_t)(row+1)*ROWH + (size_t)(pxt*32 + l31 + 1)*PXS + lk*4;
#pragma unroll
    for (int o = 0; o < 7; ++o) {
#pragma unroll
        for (int qg = 0; qg < 4; ++qg) {
            int oc0 = o*32 + 8*qg + 4*lk;
            f32x4 a4 = *(const f32x4*)(alpha + min(oc0, 192));
            f16x4 hi, lo;
#pragma unroll
            for (int e = 0; e < 4; ++e) {
                float v = acc[o][qg*4 + e];
                v = (v >= 0.f ? v : a4[e]*v) * mv;
                f16 h = (f16)v;
                hi[e] = h;
                lo[e] = (f16)(v - (float)h);
            }
            f16* p = orow + o*CBS + (qg >> 1)*K16S + (qg & 1)*KHS;
            *(f16x4*)p        = hi;
            *(f16x4*)(p + HS) = lo;
        }
    }
    // fused 1x1 epilogue: accp[px][72] init (bi1==0, +bias) or accumulate
    if (bi1 >= 0) {
        int px = row*256 + pxt*32 + l31;
        float* dst = accp + (size_t)px*72;
#pragma unroll
        for (int o = 0; o < 3; ++o) {
#pragma unroll
            for (int qg = 0; qg < 4; ++qg) {
                int oc0 = o*32 + 8*qg + 4*lk;
                if (oc0 >= 72) continue;
                f32x4 d;
#pragma unroll
                for (int e = 0; e < 4; ++e) d[e] = acc1[o][qg*4 + e];
                if (bi1 == 0) {
                    f32x4 b4;
#pragma unroll
                    for (int e = 0; e < 4; ++e) b4[e] = bias1[min(oc0 + e, 67)];
                    *(f32x4*)(dst + oc0) = d + b4;
                } else {
                    *(f32x4*)(dst + oc0) = *(const f32x4*)(dst + oc0) + d;
                }
            }
        }
    }
}

// ---------------- standalone 1x1 pass for bi=3 (outs[3]) ----------------
__global__ __launch_bounds__(256, 4)
void k_acc_last(const f16* __restrict__ in, const f16* __restrict__ pack,
                const float* __restrict__ bias, float* __restrict__ accp, int bi)
{
    int lane = threadIdx.x & 63;
    int wid  = (blockIdx.x << 2) | (threadIdx.x >> 6);
    int row  = wid >> 3;
    int col0 = (wid & 7) << 5;
    int l15 = lane & 15, lk = lane >> 4;

    f32x4 acc[5][2];
#pragma unroll
    for (int i = 0; i < 5; ++i)
#pragma unroll
        for (int j = 0; j < 2; ++j)
            acc[i][j] = (f32x4){0.f, 0.f, 0.f, 0.f};

    const f16* bb = in + (size_t)(row+1)*ROWH + (size_t)(col0 + l15 + 1)*PXS
                  + (lk >> 1)*K16S + (lk & 1)*KHS;
    const f16* ap = pack + (size_t)bi*PKL_BI + (size_t)lane*8;
    for (int cb = 0; cb < 7; ++cb) {
        f16x8 bh[2], bl[2];
#pragma unroll
        for (int pb = 0; pb < 2; ++pb) {
            const f16* p = bb + cb*CBS + pb*16*PXS;
            bh[pb] = *(const f16x8*)p;
            bl[pb] = *(const f16x8*)(p + HS);
        }
        const f16* a = ap + cb*PKL_CB;
#pragma unroll
        for (int ob = 0; ob < 5; ++ob) {
            f16x8 ah = *(const f16x8*)(a + ob*1024);
            f16x8 al = *(const f16x8*)(a + ob*1024 + 512);
#pragma unroll
            for (int pb = 0; pb < 2; ++pb) {
                acc[ob][pb] = MFMA16(ah, bh[pb], acc[ob][pb]);
                acc[ob][pb] = MFMA16(ah, bl[pb], acc[ob][pb]);
                acc[ob][pb] = MFMA16(al, bh[pb], acc[ob][pb]);
            }
        }
    }
#pragma unroll
    for (int ob = 0; ob < 5; ++ob) {
        int oc0 = ob*16 + lk*4;
        if (oc0 >= 72) continue;           // accp stride is 72 floats
#pragma unroll
        for (int pb = 0; pb < 2; ++pb) {
            int px = row*256 + col0 + pb*16 + l15;
            float* dst = accp + (size_t)px*72 + oc0;
            *(f32x4*)dst = *(const f32x4*)dst + acc[ob][pb];
        }
    }
}

// ---------------- smn = 3x3 conv(acc[4:68]) + mask_b  (plain f32) ----------------
__global__ void k_smn(const float* __restrict__ accp, const float* __restrict__ mw,
                      const float* __restrict__ mb, float* __restrict__ smn)
{
    int px = blockIdx.x*256 + threadIdx.x;
    int row = px >> 8, col = px & 255;
    float s0 = mb[0], s1 = mb[1];
    for (int ky = 0; ky < 3; ++ky) {
        int r = row + ky - 1;
        if ((unsigned)r > 255u) continue;
        for (int kx = 0; kx < 3; ++kx) {
            int c = col + kx - 1;
            if ((unsigned)c > 255u) continue;
            const float* ab = accp + ((size_t)r*256 + c)*72 + 4;
            const float* w  = mw + ky*3 + kx;
#pragma unroll
            for (int ch = 0; ch < 64; ch += 4) {
                f32x4 v = *(const f32x4*)(ab + ch);
                s0 += v[0]*w[(ch+0)*9] + v[1]*w[(ch+1)*9] + v[2]*w[(ch+2)*9] + v[3]*w[(ch+3)*9];
                s1 += v[0]*w[(64+ch+0)*9] + v[1]*w[(64+ch+1)*9] + v[2]*w[(64+ch+2)*9] + v[3]*w[(64+ch+3)*9];
            }
        }
    }
    smn[px]        = s0;
    smn[NPIX + px] = s1;
}

// ---------------- fused bilinear 2x upsample (68 ch) + mask_next → d_out -----------
__global__ void k_up(const float* __restrict__ accp, const float* __restrict__ smn,
                     const float* __restrict__ sm, float* __restrict__ outp)
{
    int o = blockIdx.x*256 + threadIdx.x;
    int oy = o >> 9, ox = o & 511;
    int my = oy >> 1, mx = ox >> 1;
    int r0, r1, c0, c1; float wy0, wy1, wx0, wx1;
    if (oy & 1) { r0 = my;            r1 = min(my+1, 255); wy0 = 0.75f; wy1 = 0.25f; }
    else        { r0 = max(my-1, 0);  r1 = my;             wy0 = 0.25f; wy1 = 0.75f; }
    if (ox & 1) { c0 = mx;            c1 = min(mx+1, 255); wx0 = 0.75f; wx1 = 0.25f; }
    else        { c0 = max(mx-1, 0);  c1 = mx;             wx0 = 0.25f; wx1 = 0.75f; }
    float w00 = wy0*wx0, w01 = wy0*wx1, w10 = wy1*wx0, w11 = wy1*wx1;
    int i00 = r0*256 + c0, i01 = r0*256 + c1, i10 = r1*256 + c0, i11 = r1*256 + c1;

    const float* p00 = accp + (size_t)i00*72;
    const float* p01 = accp + (size_t)i01*72;
    const float* p10 = accp + (size_t)i10*72;
    const float* p11 = accp + (size_t)i11*72;
#pragma unroll
    for (int ch = 0; ch < 68; ch += 4) {
        f32x4 va = *(const f32x4*)(p00 + ch);
        f32x4 vb = *(const f32x4*)(p01 + ch);
        f32x4 vc = *(const f32x4*)(p10 + ch);
        f32x4 vd = *(const f32x4*)(p11 + ch);
        f32x4 v;
#pragma unroll
        for (int r = 0; r < 4; ++r)
            v[r] = w00*va[r] + w01*vb[r] + w10*vc[r] + w11*vd[r];
        outp[(size_t)(ch+0)*262144 + o] = v[0];
        outp[(size_t)(ch+1)*262144 + o] = v[1];
        outp[(size_t)(ch+2)*262144 + o] = v[2];
        outp[(size_t)(ch+3)*262144 + o] = v[3];
    }
    float s0 = w00*smn[i00] + w01*smn[i01] + w10*smn[i10] + w11*smn[i11];
    float s1 = w00*smn[NPIX+i00] + w01*smn[NPIX+i01] + w10*smn[NPIX+i10] + w11*smn[NPIX+i11];
    outp[(size_t)68*262144 + o] = (s0 > s1) ? sm[my*256 + mx] : 0.f;
}

// ---------------- launcher ----------------
extern "C" void kernel_launch(void* const* d_in, const int* in_sizes, int n_in,
                              void* d_out, int out_size, void* d_ws, size_t ws_size,
                              hipStream_t stream)
{
    const float* feat0  = (const float*)d_in[0];
    const float* feat1  = (const float*)d_in[1];
    const float* featd  = (const float*)d_in[2];
    const float* flow   = (const float*)d_in[3];
    const float* smask  = (const float*)d_in[4];
    const float* head_w = (const float*)d_in[5];
    const float* head_a = (const float*)d_in[6];
    const float* conv_w = (const float*)d_in[7];
    const float* conv_a = (const float*)d_in[8];
    const float* last_w = (const float*)d_in[9];
    const float* last_b = (const float*)d_in[10];
    const float* mask_w = (const float*)d_in[11];
    const float* mask_b = (const float*)d_in[12];
    float* outp = (float*)d_out;

    char* ws = (char*)d_ws;
    size_t off = 0;
    f16* bufA = (f16*)(ws + off); off += SBUF;
    f16* bufB = (f16*)(ws + off); off += SBUF;
    f16* packc = (f16*)(ws + off); off += (size_t)4*PK_CONV*2;
    f16* packl = (f16*)(ws + off); off += (size_t)4*PKL_BI*2;
    f16* pack1 = (f16*)(ws + off); off += (size_t)4*PK1_BI*2;
    float* accp = (float*)(ws + off); off += (size_t)NPIX*72*4;
    float* smn  = (float*)(ws + off); off += (size_t)2*NPIX*4;

    // zero pad rows (stored rows 0 and 257) of both buffers; then halo columns
    hipMemsetAsync(bufA, 0, RBYTES, stream);
    hipMemsetAsync((char*)bufA + (size_t)257*RBYTES, 0, RBYTES, stream);
    hipMemsetAsync(bufB, 0, RBYTES, stream);
    hipMemsetAsync((char*)bufB + (size_t)257*RBYTES, 0, RBYTES, stream);
    k_zero_halo<<<226, 256, 0, stream>>>(bufA, bufB);

    k_pack_conv<<<1764, 256, 0, stream>>>(head_w, conv_w, packc);
    k_pack_last<<<70, 256, 0, stream>>>(last_w, packl);
    k_pack_last32<<<78, 256, 0, stream>>>(last_w, pack1);
    k_warp_concat<<<256, 256, 0, stream>>>(feat0, feat1, featd, flow, bufA);

    // head: x0(bufA) -> bufB = outs[0]   (no fusion)
    k_conv32<<<512, 256, 0, stream>>>(bufA, bufB, packc, head_a, smask,
                                      pack1, last_b, accp, -1);
    // layer1: bufB -> bufA = outs[1]; fused 1x1 of outs[0] (bi=0, init+bias)
    k_conv32<<<512, 256, 0, stream>>>(bufB, bufA, packc + (size_t)1*PK_CONV, conv_a, smask,
                                      pack1, last_b, accp, 0);
    // layer2: bufA -> bufB = outs[2]; fused 1x1 of outs[1] (bi=1)
    k_conv32<<<512, 256, 0, stream>>>(bufA, bufB, packc + (size_t)2*PK_CONV, conv_a + 196, smask,
                                      pack1, last_b, accp, 1);
    // layer3: bufB -> bufA = outs[3]; fused 1x1 of outs[2] (bi=2)
    k_conv32<<<512, 256, 0, stream>>>(bufB, bufA, packc + (size_t)3*PK_CONV, conv_a + 392, smask,
                                      pack1, last_b, accp, 2);
    // standalone 1x1 for outs[3]
    k_acc_last<<<512, 256, 0, stream>>>(bufA, packl, last_b, accp, 3);

    k_smn<<<256, 256, 0, stream>>>(accp, mask_w, mask_b, smn);
    k_up<<<1024, 256, 0, stream>>>(accp, smn, smask, outp);
}